// Round 9
// baseline (856.273 us; speedup 1.0000x reference)
//
#include <hip/hip_runtime.h>

#define EPS_C 0.01f
#define NU    128
#define DIN   64
#define COUT  10

typedef float    f32x4 __attribute__((ext_vector_type(4)));
typedef _Float16 f16x4 __attribute__((ext_vector_type(4)));
typedef _Float16 f16x8 __attribute__((ext_vector_type(8)));

#define MFMA32(A, B, C) __builtin_amdgcn_mfma_f32_16x16x32_f16((A), (B), (C), 0, 0, 0)
// LDS-only barrier: x prefetch global loads stay in flight (round-7 win).
#define BAR() asm volatile("s_waitcnt lgkmcnt(0)\n\ts_barrier" ::: "memory")

// TWO independent batch-groups per 1024-thread block (16 waves = 2 groups x 8).
// Each group = round-7 geometry (empirical best): 16 batch rows along MFMA n-dim,
// wave owns ONE m-tile (16 units) -> 4 tanh/lane/step. The two groups' serial
// chains (ds_read h -> MFMA -> tanh -> write -> barrier) interleave on each
// SIMD (4 waves/SIMD), hiding each other's latency under one shared barrier.
// Euler carry folded into MFMA: AT = eps*A^T, persistent f32 accumulator IS the
// master h; h_next = ha + eps - 2*eps*rcp(exp(2*wa)+1).
// mfma_f32_16x16x32_f16 layouts (HW-verified):
//   A-op: A[m=lane&15][k=quad*8+j]  B-op: B[k=quad*8+j][n=lane&15]
//   D  : D[row=quad*4+reg][col=lane&15]
// h exchange (D->B shuffle): u=16*wl+4q+r, b=lid ->
//   hbuf[gw][np][wl>>1][(2*(wl&1)+(q>>1))*16+lid][(q&1)*4+r]; reads linear b128.
__global__ __launch_bounds__(1024)
void rnn_core(const float* __restrict__ x,
              const float* __restrict__ E_w, const float* __restrict__ E_b,
              const float* __restrict__ B_p, const float* __restrict__ C_p,
              const float* __restrict__ D_w, const float* __restrict__ D_b,
              float* __restrict__ out, int T)
{
    const int tid  = threadIdx.x;
    const int lane = tid & 63;
    const int w    = tid >> 6;      // wave 0..15
    const int gw   = w >> 3;        // group 0/1
    const int wl   = w & 7;         // wave-in-group = m-tile
    const int lid  = lane & 15;
    const int q    = lane >> 4;

    // xs: [group][buf][t8][kt2][lane64][8 halves] = 2 x 2 x 16 KB
    __shared__ _Float16 xs[2][2][8 * 2 * 64 * 8];
    __shared__ _Float16 hbuf[2][2][4][64][8];   // [group][parity][kt][lane][j] 16 KB
    __shared__ float    hfin[2][16][NU + 4];

    // ---- one-time weight fragments (wave: m = 16*wl + lid) ----
    f16x8 AT[4], WT[4], EF[2];   // AT pre-scaled by eps
    f32x4 ebv;
    {
        const int m = wl * 16 + lid;
        #pragma unroll
        for (int kt = 0; kt < 4; ++kt) {
            f16x8 fa, fw;
            #pragma unroll
            for (int j = 0; j < 8; ++j) {
                const int k  = kt * 32 + q * 8 + j;
                const float dg = (k == m) ? 0.01f : 0.0f;
                const float av = B_p[k * NU + m] - 0.6f * B_p[m * NU + k] - dg;
                const float wv = C_p[k * NU + m] - 0.6f * C_p[m * NU + k] - dg;
                fa[j] = (_Float16)(EPS_C * av);   // eps folded into A
                fw[j] = (_Float16)wv;
            }
            AT[kt] = fa;  WT[kt] = fw;
        }
        #pragma unroll
        for (int kt = 0; kt < 2; ++kt) {
            f16x8 fe;
            #pragma unroll
            for (int j = 0; j < 8; ++j)
                fe[j] = (_Float16)E_w[m * DIN + kt * 32 + q * 8 + j];
            EF[kt] = fe;
        }
        #pragma unroll
        for (int r = 0; r < 4; ++r)
            ebv[r] = E_b[wl * 16 + q * 4 + r];
    }

    // ---- x staging mapping: 512 threads per group stage its chunk ----
    const int gtid = tid & 511;
    const int bb = gtid & 15;          // batch row in group
    const int s2 = (gtid >> 4) & 15;   // d-quad: d = 4*s2..4*s2+3
    const int tp = gtid >> 8;          // step parity within chunk
    const int g0 = blockIdx.x * 32 + gw * 16;
    const float* xrow = x + ((size_t)(g0 + bb) * T) * DIN + s2 * 4;
    const int wb2 = (((s2 >> 3) * 64) + (((s2 >> 1) & 3) * 16) + bb) * 16 + (s2 & 1) * 8;

    float4 xg[4];   // 4 steps/thread of an 8-step chunk (steps 2*i2+tp)

    // ---- init: zero parity-0 h buffers; stage chunk 0 ----
    if (tid < 256)
        ((float4*)&hbuf[0][0][0][0][0])[tid] = (float4){0.f, 0.f, 0.f, 0.f};
    else if (tid < 512)
        ((float4*)&hbuf[1][0][0][0][0])[tid - 256] = (float4){0.f, 0.f, 0.f, 0.f};
    #pragma unroll
    for (int i2 = 0; i2 < 4; ++i2)
        xg[i2] = *(const float4*)(xrow + (size_t)(2 * i2 + tp) * DIN);
    {
        char* base_ = (char*)&xs[gw][0][0];
        #pragma unroll
        for (int i2 = 0; i2 < 4; ++i2) {
            float4 v_ = xg[i2];
            f16x4 h4_;
            h4_[0] = (_Float16)v_.x; h4_[1] = (_Float16)v_.y;
            h4_[2] = (_Float16)v_.z; h4_[3] = (_Float16)v_.w;
            *(f16x4*)(base_ + (2 * i2 + tp) * 2048 + wb2) = h4_;
        }
    }
    __syncthreads();

    // ---- state: ha = master h (f32, D layout) = 0 ; zc = z(0) ----
    f32x4 ha = {0.f, 0.f, 0.f, 0.f};
    f32x4 zc;
    {
        f16x8 x0 = *(const f16x8*)((char*)&xs[gw][0][0] + (0 * 64 + lane) * 16);
        f16x8 x1 = *(const f16x8*)((char*)&xs[gw][0][0] + (1 * 64 + lane) * 16);
        zc = ebv;
        zc = MFMA32(EF[0], x0, zc);
        zc = MFMA32(EF[1], x1, zc);
    }

    const int nch = T >> 3;   // 128 chunks of 8 steps
    for (int c = 0; c < nch; ++c) {
        if (c + 1 < nch) {
            #pragma unroll
            for (int i2 = 0; i2 < 4; ++i2)
                xg[i2] = *(const float4*)(xrow + (size_t)((c + 1) * 8 + 2 * i2 + tp) * DIN);
        }
        #pragma unroll
        for (int i = 0; i < 8; ++i) {
            const int t  = c * 8 + i;
            const int p  = i & 1;
            const int np = p ^ 1;

            // h B-frags (linear ds_read_b128, conflict-free)
            f16x8 hB[4];
            #pragma unroll
            for (int kt = 0; kt < 4; ++kt)
                hB[kt] = *(const f16x8*)((char*)&hbuf[gw][p][0][0][0] + (kt * 64 + lane) * 16);

            // x B-frags for t+1 (z_next, off critical path)
            int tt = t + 1; if (tt >= T) tt = T - 1;
            const int it = tt & 7;
            char* xb = (char*)&xs[gw][(tt >> 3) & 1][0];
            f16x8 xfA = *(const f16x8*)(xb + ((it * 2 + 0) * 64 + lane) * 16);
            f16x8 xfB = *(const f16x8*)(xb + ((it * 2 + 1) * 64 + lane) * 16);

            // ---- wa chain FIRST (tanh can start while ya chain runs) ----
            f32x4 wa = zc;
            #pragma unroll
            for (int kt = 0; kt < 4; ++kt)
                wa = MFMA32(WT[kt], hB[kt], wa);
            // ya chain: C = ha (master h) -> ha_next_pre = h + eps*A^T h
            #pragma unroll
            for (int kt = 0; kt < 4; ++kt)
                ha = MFMA32(AT[kt], hB[kt], ha);

            // ---- epilogue: ha += eps - 2*eps*rcp(exp(2*wa)+1); write D->B ----
            {
                f16x4 nh;
                #pragma unroll
                for (int r = 0; r < 4; ++r) {
                    const float e2 = __expf(2.0f * wa[r]);
                    const float rc = __builtin_amdgcn_rcpf(e2 + 1.0f);
                    const float hv = fmaf(-2.0f * EPS_C, rc, ha[r] + EPS_C);
                    ha[r] = hv;
                    nh[r] = (_Float16)hv;
                }
                char* hwp = (char*)&hbuf[gw][np][wl >> 1][0][0];
                const int row = (2 * (wl & 1) + (q >> 1)) * 16 + lid;
                *(f16x4*)(hwp + row * 16 + (q & 1) * 8) = nh;
            }

            // z(t+1): independent MFMAs fill the pre-barrier window
            {
                f32x4 zn = ebv;
                zn = MFMA32(EF[0], xfA, zn);
                zn = MFMA32(EF[1], xfB, zn);
                zc = zn;
            }

            // staging for next chunk: one f16x4 write per step, steps 4..7
            if (c + 1 < nch && i >= 4) {
                const int i2 = i - 4;
                float4 v_ = xg[i2];
                f16x4 h4_;
                h4_[0] = (_Float16)v_.x; h4_[1] = (_Float16)v_.y;
                h4_[2] = (_Float16)v_.z; h4_[3] = (_Float16)v_.w;
                *(f16x4*)((char*)&xs[gw][(c + 1) & 1][0] + (2 * i2 + tp) * 2048 + wb2) = h4_;
            }
            BAR();   // lgkmcnt(0) + s_barrier; vmcnt stays in flight
        }
    }

    // ---- final: stash h, small output GEMM ----
    #pragma unroll
    for (int r = 0; r < 4; ++r)
        hfin[gw][lid][wl * 16 + q * 4 + r] = ha[r];
    __syncthreads();

    if (tid < 2 * 16 * COUT) {
        const int gg  = tid / 160;
        const int rem = tid - gg * 160;
        const int r   = rem / COUT;
        const int cc  = rem - r * COUT;
        float acc = D_b[cc];
        #pragma unroll 8
        for (int u = 0; u < NU; ++u)
            acc = fmaf(hfin[gg][r][u], D_w[cc * NU + u], acc);
        out[((size_t)(blockIdx.x * 32 + gg * 16 + r)) * COUT + cc] = acc;
    }
}

extern "C" void kernel_launch(void* const* d_in, const int* in_sizes, int n_in,
                              void* d_out, int out_size, void* d_ws, size_t ws_size,
                              hipStream_t stream)
{
    const float* x   = (const float*)d_in[0];
    const float* E_w = (const float*)d_in[1];
    const float* E_b = (const float*)d_in[2];
    const float* B_p = (const float*)d_in[3];
    const float* C_p = (const float*)d_in[4];
    const float* D_w = (const float*)d_in[5];
    const float* D_b = (const float*)d_in[6];
    float* out = (float*)d_out;

    const int B  = out_size / COUT;            // 512
    const int T  = in_sizes[0] / (B * DIN);    // 1024
    const int NB = B / 32;                     // 16 blocks (2 groups each)

    rnn_core<<<NB, 1024, 0, stream>>>(x, E_w, E_b, B_p, C_p, D_w, D_b, out, T);
}